// Round 16
// baseline (233.107 us; speedup 1.0000x reference)
//
#include <hip/hip_runtime.h>
#include <hip/hip_bf16.h>
#include <stdint.h>

// ---------------------------------------------------------------------------
// SelfAttention: X[4,2048,256] fp32; Wq/Wk/Wv [256,2048]; Wo [2048,256]; bo[256]
//   prep:  Xb = bf16(X)  +  Wqt/Wkt = bf16(qs*W^T), Wvt/Wot = bf16(W^T)
//   qk = Xb @ [Wqt;Wkt]^T  [8192][4096] bf16 ; vt = Wvt @ Xb^T [2048][8192]
//   attn2: 4 waves x 32 q-rows per block, 2 blocks/CU. KVBLK=32, dbuf LDS,
//          32x32x16 MFMA, swapped QK^T, QK(t)||PV(t-1), in-reg softmax (exp2).
//          R16: setprio REMOVED (lockstep block -> T5 inapplicable, m190).
//   out = ctx @ Wot^T + bo  fp32  -- 64x64 tile: 512 blocks (2/CU)
// ---------------------------------------------------------------------------

using short8 = __attribute__((ext_vector_type(8))) short;   // 8 bf16 = 4 VGPR
using f32x4  = __attribute__((ext_vector_type(4))) float;
using f32x16 = __attribute__((ext_vector_type(16))) float;

#define MFMA16(a, b, c) __builtin_amdgcn_mfma_f32_16x16x32_bf16((a), (b), (c), 0, 0, 0)
#define MFMA32(a, b, c) __builtin_amdgcn_mfma_f32_32x32x16_bf16((a), (b), (c), 0, 0, 0)

#if __has_builtin(__builtin_amdgcn_exp2f)
#define EXP2(x) __builtin_amdgcn_exp2f(x)
#else
#define EXP2(x) exp2f(x)
#endif

__device__ __forceinline__ uint16_t f2bf(float f) {
  union { float f; uint32_t u; } v; v.f = f;
  uint32_t u = v.u;
  u += 0x7fffu + ((u >> 16) & 1u);     // round-to-nearest-even
  return (uint16_t)(u >> 16);
}

__device__ __forceinline__ uint32_t cvtpk_bf16(float lo, float hi) {
  uint32_t r;
  asm("v_cvt_pk_bf16_f32 %0, %1, %2" : "=v"(r) : "v"(lo), "v"(hi));
  return r;
}

// swap a's hi-32-lane half with b's lo-32-lane half (both operands updated)
__device__ __forceinline__ void swap32(uint32_t& a, uint32_t& b) {
  asm volatile("v_permlane32_swap_b32 %0, %1" : "+v"(a), "+v"(b));
}

// global -> LDS direct (16B per lane; LDS dest = wave-uniform base + lane*16)
__device__ __forceinline__ void gll16(const void* g, void* l) {
  __builtin_amdgcn_global_load_lds(
      (const __attribute__((address_space(1))) void*)g,
      (__attribute__((address_space(3))) void*)l, 16, 0, 0);
}

// ---------------------------------------------------------------------------
// prep: blocks [0,2048) cast X -> Xb (bf16, vectorized);
//       blocks [2048,2432): tcast Wq/Wk/Wv; [2432,2560): tcast Wo.
__global__ __launch_bounds__(256) void prep_k(const float* __restrict__ X,
                                              uint16_t* __restrict__ Xb,
                                              const float* __restrict__ Wq,
                                              const float* __restrict__ Wk,
                                              const float* __restrict__ Wv,
                                              const float* __restrict__ Wo,
                                              uint16_t* __restrict__ Wt3,
                                              uint16_t* __restrict__ Wot,
                                              float qs) {
  const int b = blockIdx.x;
  const int tid = threadIdx.x;
  if (b < 2048) {
    int i = b * 256 + tid;               // n4 = 2048*256 exactly
    float4 v = ((const float4*)X)[i];
    union { uint16_t u[4]; uint2 p; } r;
    r.u[0] = f2bf(v.x); r.u[1] = f2bf(v.y); r.u[2] = f2bf(v.z); r.u[3] = f2bf(v.w);
    ((uint2*)Xb)[i] = r.p;
    return;
  }
  __shared__ float T[64][65];
  const int bb = b - 2048;
  const float* W;
  uint16_t* Wt;
  int R, C, c0, r0;
  float scale;
  if (bb < 384) {
    const int z = bb >> 7, rem = bb & 127;
    W = (z == 0) ? Wq : (z == 1) ? Wk : Wv;
    scale = (z == 2) ? 1.0f : qs;
    R = 256; C = 2048;
    Wt = Wt3 + (size_t)z * C * R;
    c0 = (rem & 31) * 64; r0 = (rem >> 5) * 64;
  } else {
    const int rem = bb - 384;
    W = Wo; scale = 1.0f;
    R = 2048; C = 256;
    Wt = Wot;
    c0 = (rem & 3) * 64; r0 = (rem >> 2) * 64;
  }
  int cc = tid & 63;
  for (int rr = tid >> 6; rr < 64; rr += 4)
    T[rr][cc] = W[(size_t)(r0 + rr) * C + c0 + cc];
  __syncthreads();
  int n = tid >> 2, kb = (tid & 3) * 16;
  uint16_t* orow = Wt + (size_t)(c0 + n) * R + r0 + kb;
#pragma unroll
  for (int j = 0; j < 16; ++j) orow[j] = f2bf(T[kb + j][n] * scale);
}

// ---------------------------------------------------------------------------
// GEMM body: C[m][n] = sum_k A[m][k]*Bt[n][k]; (MT*32) x (NT*32) tile, 4 waves
// in a 2x2 wave grid (wave owns (MT*16) x (NT*16) sub-tile). BK=64.
template <int EPI, int MT, int NT>
__device__ __forceinline__ void gemm_body(const uint16_t* __restrict__ A,
                                          const uint16_t* __restrict__ Bt,
                                          void* __restrict__ Cv,
                                          const float* __restrict__ bias,
                                          int M, int N, int K, int bx, int by,
                                          uint16_t* As, uint16_t* Bs) {
  const int tid = threadIdx.x;
  const int wv = tid >> 6, lane = tid & 63;
  const int ql = lane & 15, gq = lane >> 4;
  const int wr = wv >> 1, wc = wv & 1;
  const int m0 = by * (MT * 32), n0 = bx * (NT * 32);

  f32x4 acc[MT][NT];
#pragma unroll
  for (int i = 0; i < MT; ++i)
#pragma unroll
    for (int j = 0; j < NT; ++j) acc[i][j] = (f32x4){0.f, 0.f, 0.f, 0.f};

  const int nkb = K >> 6;
  for (int kb = 0; kb < nkb; ++kb) {
#pragma unroll
    for (int j = 0; j < MT; ++j) {
      int s = (wv * MT + j) * 64 + lane;
      int row = s >> 3, c = s & 7;
      int gc = c ^ (row & 7);
      gll16(A + (size_t)(m0 + row) * K + kb * 64 + gc * 8, &As[(wv * MT + j) * 512]);
    }
#pragma unroll
    for (int j = 0; j < NT; ++j) {
      int s = (wv * NT + j) * 64 + lane;
      int row = s >> 3, c = s & 7;
      int gc = c ^ (row & 7);
      gll16(Bt + (size_t)(n0 + row) * K + kb * 64 + gc * 8, &Bs[(wv * NT + j) * 512]);
    }
    __syncthreads();

    short8 af[MT][2], bf[NT][2];
#pragma unroll
    for (int mt = 0; mt < MT; ++mt)
#pragma unroll
      for (int kk = 0; kk < 2; ++kk) {
        int row = wr * (MT * 16) + mt * 16 + ql;
        int c = (kk * 4 + gq) ^ (row & 7);
        af[mt][kk] = *(const short8*)&As[row * 64 + c * 8];
      }
#pragma unroll
    for (int nt = 0; nt < NT; ++nt)
#pragma unroll
      for (int kk = 0; kk < 2; ++kk) {
        int row = wc * (NT * 16) + nt * 16 + ql;
        int c = (kk * 4 + gq) ^ (row & 7);
        bf[nt][kk] = *(const short8*)&Bs[row * 64 + c * 8];
      }
#pragma unroll
    for (int kk = 0; kk < 2; ++kk)
#pragma unroll
      for (int mt = 0; mt < MT; ++mt)
#pragma unroll
        for (int nt = 0; nt < NT; ++nt)
          acc[mt][nt] = MFMA16(af[mt][kk], bf[nt][kk], acc[mt][nt]);
    __syncthreads();
  }

#pragma unroll
  for (int mt = 0; mt < MT; ++mt)
#pragma unroll
    for (int nt = 0; nt < NT; ++nt)
#pragma unroll
      for (int r = 0; r < 4; ++r) {
        int m = m0 + wr * (MT * 16) + mt * 16 + gq * 4 + r;
        int n = n0 + wc * (NT * 16) + nt * 16 + ql;
        float v = acc[mt][nt][r];
        if (EPI == 0) {
          ((uint16_t*)Cv)[(size_t)m * N + n] = f2bf(v);
        } else {
          ((float*)Cv)[(size_t)m * N + n] = v + bias[n];
        }
      }
}

// merged projections: 3072 blocks.
//  b < 2048: qk = Xb @ Wqkt^T  [8192][4096]  (bx=b&31, by=b>>5)
//  else    : vt = Wvt @ Xb^T   [2048][8192]  (bx=rem&63, by=rem>>6)
__global__ __launch_bounds__(256) void proj_all_k(const uint16_t* __restrict__ Xb,
                                                  const uint16_t* __restrict__ Wqkt,
                                                  const uint16_t* __restrict__ Wvt,
                                                  uint16_t* __restrict__ qkw,
                                                  uint16_t* __restrict__ vtws) {
  __shared__ uint16_t As[128 * 64];
  __shared__ uint16_t Bs[4 * 32 * 64];
  const int b = blockIdx.x;
  if (b < 2048) {
    gemm_body<0, 4, 4>(Xb, Wqkt, qkw, nullptr, 8192, 4096, 256,
                       b & 31, b >> 5, As, Bs);
  } else {
    const int rem = b - 2048;
    gemm_body<0, 4, 4>(Wvt, Xb, vtws, nullptr, 2048, 8192, 256,
                       rem & 63, rem >> 6, As, Bs);
  }
}

// out projection: 64x64 tile (MT=2,NT=2), grid (4, 128) = 512 blocks (2/CU)
__global__ __launch_bounds__(256) void gemm_out_k(const uint16_t* __restrict__ A,
                                                  const uint16_t* __restrict__ Bt,
                                                  float* __restrict__ Cv,
                                                  const float* __restrict__ bias,
                                                  int M, int N, int K) {
  __shared__ uint16_t As[2 * 32 * 64];
  __shared__ uint16_t Bs[2 * 32 * 64];
  gemm_body<1, 2, 2>(A, Bt, Cv, bias, M, N, K, blockIdx.x, blockIdx.y, As, Bs);
}

// ---------------------------------------------------------------------------
// attn2: block = 256 thr (4 waves); wave owns 32 q-rows; block = 128 q-rows.
// 512 blocks -> 2 blocks/CU (independent barrier domains). KVBLK=32, 64 tiles.
// Swapped QK: S^T[key][q] = mfma(Kfrag, Qfrag); lane(q=l31) holds one q-col.
// Pipeline: body(t) = stage K(t+1),V(t) -> {QK(t) || PV(t-1)} -> SM(t) -> bar.
// K [32 keys][256 d] rows 512B, XOR32 (uniform bank quads). V [256 d][32 keys]
// rows 64B, swizzle g(d)=(d>>1)&3 -> uniform bank quads (4 lanes/quad).
// No setprio: lockstep 4-wave block -> T5 inapplicable (m190).
__global__ __launch_bounds__(256, 2) void attn2_k(const uint16_t* __restrict__ qk,
                                                  const uint16_t* __restrict__ vtws,
                                                  uint16_t* __restrict__ ctx,
                                                  int b0, int nb) {
  __shared__ uint16_t Ks[2][32 * 256];   // 16KB/buf; chunk c at c^row
  __shared__ uint16_t Vts[2][256 * 32];  // 16KB/buf; chunk c at c^((d>>1)&3)
  const int S = 2048;
  // XCD-grouped decode: h == blockIdx%8 == XCD -> each XCD's L2 holds 1 head
  const int h = blockIdx.x & 7;
  const int t = blockIdx.x >> 3;
  const int bb = t >> 4, qb = t & 15;    // 16 q-blocks of 128 rows
  const int tid = threadIdx.x, w = tid >> 6, lane = tid & 63;
  const int l31 = lane & 31, hi = lane >> 5;
  const size_t SN = (size_t)nb * S;

  // ---- Q fragments (B-operand): Q[q=l31][ds*16 + hi*8 .. +7], 16 d-slots
  short8 qf[16];
  {
    const uint16_t* qrow =
        qk + (size_t)(bb * S + qb * 128 + w * 32 + l31) * 4096 + h * 256 + hi * 8;
#pragma unroll
    for (int ds = 0; ds < 16; ++ds) qf[ds] = *(const short8*)(qrow + ds * 16);
  }

  // ---- per-lane staging byte-offsets (hoisted; step per k-tile is uniform)
  uint32_t ok[4], ov[4];
#pragma unroll
  for (int j = 0; j < 4; ++j) {
    int s = (j * 4 + w) * 64 + lane;    // chunk 0..1023 within 16KB tile
    int krw = s >> 5, kc = s & 31;      // K: row(key 0..31), slot(0..31)
    int kgc = kc ^ krw;                 // inverse of XOR32 read swizzle
    ok[j] = (uint32_t)(((bb * S + krw) * 4096 + 2048 + h * 256 + kgc * 8) * 2);
    int d = s >> 2, vc = s & 3;         // V: row(d 0..255), slot(0..3)
    int cg = vc ^ ((d >> 1) & 3);       // uniform bank-quad swizzle
    ov[j] = (uint32_t)((((h * 256 + d) * SN) + (size_t)bb * S + cg * 8) * 2);
  }
  const uint32_t kstep = 32 * 4096 * 2;  // 32 key-rows (qk row stride 4096)
  const uint32_t vstep = 32 * 2;         // 32 key-cols

  const char* kgbase = (const char*)qk;
  const char* vgbase = (const char*)vtws;

  auto stageK = [&](int buf, int kb) {
#pragma unroll
    for (int j = 0; j < 4; ++j)
      gll16(kgbase + ok[j] + (uint32_t)kb * kstep, &Ks[buf][(j * 4 + w) * 512]);
  };
  auto stageV = [&](int buf, int kb) {
#pragma unroll
    for (int j = 0; j < 4; ++j)
      gll16(vgbase + ov[j] + (uint32_t)kb * vstep, &Vts[buf][(j * 4 + w) * 512]);
  };

  f32x16 cacc[8];
#pragma unroll
  for (int db = 0; db < 8; ++db)
#pragma unroll
    for (int r = 0; r < 16; ++r) cacc[db][r] = 0.f;
  float m_run = -3e38f, l_run = 0.f;
  short8 pa0, pa1;                       // packed P(t-1), persists across tiles

  const int kx = l31 << 4;               // K read XOR32 (row = l31)
  const int vx = ((l31 >> 1) & 3) << 4;  // V read swizzle g(d)=(d>>1)&3
  const int hi16 = hi << 4;

  f32x16 sA;

  // ---- QK(t) alone (prologue tile): 16-MFMA chain over K[cur]
  auto qk_only = [&](int cur) {
    const char* kr = (const char*)Ks[cur] + l31 * 512;
#pragma unroll
    for (int r = 0; r < 16; ++r) sA[r] = 0.f;
#pragma unroll
    for (int i = 0; i < 16; ++i) {
      int off = (i * 32 + hi16) ^ kx;
      sA = MFMA32(*(const short8*)(kr + off), qf[i], sA);
    }
  };

  // ---- QK(t) interleaved with PV(t-1) (pa0,pa1 against Vts[cur^1])
  auto qk_pv = [&](int cur) {
    const char* kr = (const char*)Ks[cur] + l31 * 512;
    const char* vb = (const char*)Vts[cur ^ 1];
#pragma unroll
    for (int r = 0; r < 16; ++r) sA[r] = 0.f;
#pragma unroll
    for (int i = 0; i < 16; ++i) {
      int off = (i * 32 + hi16) ^ kx;
      sA = MFMA32(*(const short8*)(kr + off), qf[i], sA);
      const int ks = i >> 3, db = i & 7;       // compile-time in unroll
      int voff = ((ks * 2 + hi) << 4) ^ vx;
      short8 vf = *(const short8*)(vb + (db * 32 + l31) * 64 + voff);
      cacc[db] = MFMA32(ks ? pa1 : pa0, vf, cacc[db]);
    }
  };

  // ---- PV(t) alone (epilogue tile), V in Vts[slot]
  auto pv_only = [&](int slot) {
    const char* vb = (const char*)Vts[slot];
#pragma unroll
    for (int ks = 0; ks < 2; ++ks) {
      int voff = ((ks * 2 + hi) << 4) ^ vx;
      short8 p = ks ? pa1 : pa0;
#pragma unroll
      for (int db = 0; db < 8; ++db) {
        short8 vf = *(const short8*)(vb + (db * 32 + l31) * 64 + voff);
        cacc[db] = MFMA32(p, vf, cacc[db]);
      }
    }
  };

  // ---- softmax (log2 domain) + pack into pa0,pa1
  auto sm_pack = [&]() {
    float pm = fmaxf(
        fmaxf(fmaxf(fmaxf(sA[0], sA[1]), fmaxf(sA[2], sA[3])),
              fmaxf(fmaxf(sA[4], sA[5]), fmaxf(sA[6], sA[7]))),
        fmaxf(fmaxf(fmaxf(sA[8], sA[9]), fmaxf(sA[10], sA[11])),
              fmaxf(fmaxf(sA[12], sA[13]), fmaxf(sA[14], sA[15]))));
    pm = fmaxf(pm, __shfl_xor(pm, 32));

    if (__any(pm - m_run > 8.0f)) {      // defer-max: rescale only on growth
      float mn = fmaxf(m_run, pm);
      float al = EXP2(m_run - mn);
      m_run = mn;
      l_run *= al;
#pragma unroll
      for (int r = 0; r < 16; ++r) {
        float a = __shfl(al, (r & 3) + 8 * (r >> 2) + 4 * hi);
#pragma unroll
        for (int db = 0; db < 8; ++db) cacc[db][r] *= a;
      }
    }

    float ps = 0.f;
#pragma unroll
    for (int r = 0; r < 16; ++r) { sA[r] = EXP2(sA[r] - m_run); ps += sA[r]; }
    ps += __shfl_xor(ps, 32);
    l_run += ps;

    uint32_t W[4][2];
#pragma unroll
    for (int g = 0; g < 4; ++g) {
      W[g][0] = cvtpk_bf16(sA[4 * g], sA[4 * g + 1]);
      W[g][1] = cvtpk_bf16(sA[4 * g + 2], sA[4 * g + 3]);
    }
    swap32(W[0][0], W[1][0]); swap32(W[0][1], W[1][1]);
    swap32(W[2][0], W[3][0]); swap32(W[2][1], W[3][1]);
    union U { uint32_t u[4]; short8 v; };
    U a0, a1;
    a0.u[0] = W[0][0]; a0.u[1] = W[0][1]; a0.u[2] = W[1][0]; a0.u[3] = W[1][1];
    a1.u[0] = W[2][0]; a1.u[1] = W[2][1]; a1.u[2] = W[3][0]; a1.u[3] = W[3][1];
    pa0 = a0.v; pa1 = a1.v;
  };

  // ---- pipeline
  stageK(0, 0);
  __syncthreads();                        // K(0) ready

  // body(0): stage K(1),V(0); QK(0); SM(0); barrier
  stageK(1, 1);
  stageV(0, 0);
  qk_only(0);
  sm_pack();
  __syncthreads();                        // K(1), V(0) ready

  for (int tt = 1; tt < 64; ++tt) {
    const int cur = tt & 1;
    if (tt < 63) stageK(cur ^ 1, tt + 1);
    stageV(cur, tt);
    qk_pv(cur);                           // QK(tt) || PV(tt-1)
    sm_pack();
    __syncthreads();
  }
  pv_only(1);                             // PV(63), V in Vts[63&1]

  // ---- epilogue: O[q][d] = cacc/l ; q in reg-dim -> broadcast 1/l per row
  float linv = 1.f / l_run;
  uint16_t* crow = ctx + (size_t)((b0 + bb) * S + qb * 128 + w * 32) * 2048 + h * 256;
#pragma unroll
  for (int r = 0; r < 16; ++r) {
    int qr = (r & 3) + 8 * (r >> 2) + 4 * hi;
    float lr = __shfl(linv, qr);
#pragma unroll
    for (int db = 0; db < 8; ++db)
      crow[(size_t)qr * 2048 + db * 32 + l31] = f2bf(cacc[db][r] * lr);
  }
}

// ---------------------------------------------------------------------------
extern "C" void kernel_launch(void* const* d_in, const int* in_sizes, int n_in,
                              void* d_out, int out_size, void* d_ws, size_t ws_size,
                              hipStream_t stream) {
  const float* X  = (const float*)d_in[0];
  const float* Wq = (const float*)d_in[1];
  const float* Wk = (const float*)d_in[2];
  const float* Wv = (const float*)d_in[3];
  const float* Wo = (const float*)d_in[4];
  const float* bo = (const float*)d_in[5];
  float* out = (float*)d_out;

  const int B = 4, S = 2048, Dm = 256, DH = 2048;
  (void)in_sizes; (void)n_in; (void)out_size; (void)ws_size;

  uint16_t* p = (uint16_t*)d_ws;
  uint16_t* Xb  = p; p += (size_t)B * S * Dm;
  uint16_t* Wqt = p; p += (size_t)DH * Dm;   // Wqt,Wkt,Wvt contiguous
  uint16_t* Wkt = p; p += (size_t)DH * Dm;
  uint16_t* Wvt = p; p += (size_t)DH * Dm;
  uint16_t* Wot = p; p += (size_t)Dm * DH;
  uint16_t* ctx = p; p += (size_t)B * S * DH;
  uint16_t* qkw = p; p += (size_t)B * S * (2 * DH);  // [8192][4096]
  uint16_t* vtws = p;                                // [2048][8192]
  (void)Wkt;

  // sqrt(log2e) folded into q,k scales -> scores in log2 domain
  const float qs = 0.25f * 1.2011224087864498f;

  // prep: X cast (2048 blocks) + all weight transpose-casts (512 blocks)
  prep_k<<<dim3(2560), 256, 0, stream>>>(X, Xb, Wq, Wk, Wv, Wo, Wqt, Wot, qs);
  // merged projections: qk [8192][4096] (2048 blocks) + vt [2048][8192] (1024)
  proj_all_k<<<dim3(3072), 256, 0, stream>>>(Xb, Wqt, Wvt, qkw, vtws);
  attn2_k<<<dim3(512), 256, 0, stream>>>(qkw, vtws, ctx, 0, B);
  // out projection: 64x64 tiles -> grid (4, 128) = 512 blocks (2 per CU)
  gemm_out_k<<<dim3(Dm / 64, (B * S) / 64), 256, 0, stream>>>(
      ctx, Wot, out, bo, B * S, Dm, DH);
}

// Round 17
// 231.696 us; speedup vs baseline: 1.0061x; 1.0061x over previous
//
#include <hip/hip_runtime.h>
#include <hip/hip_bf16.h>
#include <stdint.h>

// ---------------------------------------------------------------------------
// SelfAttention: X[4,2048,256] fp32; Wq/Wk/Wv [256,2048]; Wo [2048,256]; bo[256]
//   prep:  Xb = bf16(X)  +  Wqt/Wkt = bf16(qs*W^T), Wvt/Wot = bf16(W^T)
//   qk = Xb @ [Wqt;Wkt]^T  [8192][4096] bf16 ; vt = Wvt @ Xb^T [2048][8192]
//   attn2: 4 waves x 32 q-rows per block, 2 blocks/CU. KVBLK=32, dbuf LDS,
//          32x32x16 MFMA, swapped QK^T, QK(t)||PV(t-1), in-reg softmax (exp2).
//   out = ctx @ Wot^T + bo  fp32  -- 64x64 tile: 512 blocks (2/CU)
// Final configuration (best measured: 232.0us, R15).
// ---------------------------------------------------------------------------

using short8 = __attribute__((ext_vector_type(8))) short;   // 8 bf16 = 4 VGPR
using f32x4  = __attribute__((ext_vector_type(4))) float;
using f32x16 = __attribute__((ext_vector_type(16))) float;

#define MFMA16(a, b, c) __builtin_amdgcn_mfma_f32_16x16x32_bf16((a), (b), (c), 0, 0, 0)
#define MFMA32(a, b, c) __builtin_amdgcn_mfma_f32_32x32x16_bf16((a), (b), (c), 0, 0, 0)

#if __has_builtin(__builtin_amdgcn_exp2f)
#define EXP2(x) __builtin_amdgcn_exp2f(x)
#else
#define EXP2(x) exp2f(x)
#endif

__device__ __forceinline__ uint16_t f2bf(float f) {
  union { float f; uint32_t u; } v; v.f = f;
  uint32_t u = v.u;
  u += 0x7fffu + ((u >> 16) & 1u);     // round-to-nearest-even
  return (uint16_t)(u >> 16);
}

__device__ __forceinline__ uint32_t cvtpk_bf16(float lo, float hi) {
  uint32_t r;
  asm("v_cvt_pk_bf16_f32 %0, %1, %2" : "=v"(r) : "v"(lo), "v"(hi));
  return r;
}

// swap a's hi-32-lane half with b's lo-32-lane half (both operands updated)
__device__ __forceinline__ void swap32(uint32_t& a, uint32_t& b) {
  asm volatile("v_permlane32_swap_b32 %0, %1" : "+v"(a), "+v"(b));
}

// global -> LDS direct (16B per lane; LDS dest = wave-uniform base + lane*16)
__device__ __forceinline__ void gll16(const void* g, void* l) {
  __builtin_amdgcn_global_load_lds(
      (const __attribute__((address_space(1))) void*)g,
      (__attribute__((address_space(3))) void*)l, 16, 0, 0);
}

// ---------------------------------------------------------------------------
// prep: blocks [0,2048) cast X -> Xb (bf16, vectorized);
//       blocks [2048,2432): tcast Wq/Wk/Wv; [2432,2560): tcast Wo.
__global__ __launch_bounds__(256) void prep_k(const float* __restrict__ X,
                                              uint16_t* __restrict__ Xb,
                                              const float* __restrict__ Wq,
                                              const float* __restrict__ Wk,
                                              const float* __restrict__ Wv,
                                              const float* __restrict__ Wo,
                                              uint16_t* __restrict__ Wt3,
                                              uint16_t* __restrict__ Wot,
                                              float qs) {
  const int b = blockIdx.x;
  const int tid = threadIdx.x;
  if (b < 2048) {
    int i = b * 256 + tid;               // n4 = 2048*256 exactly
    float4 v = ((const float4*)X)[i];
    union { uint16_t u[4]; uint2 p; } r;
    r.u[0] = f2bf(v.x); r.u[1] = f2bf(v.y); r.u[2] = f2bf(v.z); r.u[3] = f2bf(v.w);
    ((uint2*)Xb)[i] = r.p;
    return;
  }
  __shared__ float T[64][65];
  const int bb = b - 2048;
  const float* W;
  uint16_t* Wt;
  int R, C, c0, r0;
  float scale;
  if (bb < 384) {
    const int z = bb >> 7, rem = bb & 127;
    W = (z == 0) ? Wq : (z == 1) ? Wk : Wv;
    scale = (z == 2) ? 1.0f : qs;
    R = 256; C = 2048;
    Wt = Wt3 + (size_t)z * C * R;
    c0 = (rem & 31) * 64; r0 = (rem >> 5) * 64;
  } else {
    const int rem = bb - 384;
    W = Wo; scale = 1.0f;
    R = 2048; C = 256;
    Wt = Wot;
    c0 = (rem & 3) * 64; r0 = (rem >> 2) * 64;
  }
  int cc = tid & 63;
  for (int rr = tid >> 6; rr < 64; rr += 4)
    T[rr][cc] = W[(size_t)(r0 + rr) * C + c0 + cc];
  __syncthreads();
  int n = tid >> 2, kb = (tid & 3) * 16;
  uint16_t* orow = Wt + (size_t)(c0 + n) * R + r0 + kb;
#pragma unroll
  for (int j = 0; j < 16; ++j) orow[j] = f2bf(T[kb + j][n] * scale);
}

// ---------------------------------------------------------------------------
// GEMM body: C[m][n] = sum_k A[m][k]*Bt[n][k]; (MT*32) x (NT*32) tile, 4 waves
// in a 2x2 wave grid (wave owns (MT*16) x (NT*16) sub-tile). BK=64.
template <int EPI, int MT, int NT>
__device__ __forceinline__ void gemm_body(const uint16_t* __restrict__ A,
                                          const uint16_t* __restrict__ Bt,
                                          void* __restrict__ Cv,
                                          const float* __restrict__ bias,
                                          int M, int N, int K, int bx, int by,
                                          uint16_t* As, uint16_t* Bs) {
  const int tid = threadIdx.x;
  const int wv = tid >> 6, lane = tid & 63;
  const int ql = lane & 15, gq = lane >> 4;
  const int wr = wv >> 1, wc = wv & 1;
  const int m0 = by * (MT * 32), n0 = bx * (NT * 32);

  f32x4 acc[MT][NT];
#pragma unroll
  for (int i = 0; i < MT; ++i)
#pragma unroll
    for (int j = 0; j < NT; ++j) acc[i][j] = (f32x4){0.f, 0.f, 0.f, 0.f};

  const int nkb = K >> 6;
  for (int kb = 0; kb < nkb; ++kb) {
#pragma unroll
    for (int j = 0; j < MT; ++j) {
      int s = (wv * MT + j) * 64 + lane;
      int row = s >> 3, c = s & 7;
      int gc = c ^ (row & 7);
      gll16(A + (size_t)(m0 + row) * K + kb * 64 + gc * 8, &As[(wv * MT + j) * 512]);
    }
#pragma unroll
    for (int j = 0; j < NT; ++j) {
      int s = (wv * NT + j) * 64 + lane;
      int row = s >> 3, c = s & 7;
      int gc = c ^ (row & 7);
      gll16(Bt + (size_t)(n0 + row) * K + kb * 64 + gc * 8, &Bs[(wv * NT + j) * 512]);
    }
    __syncthreads();

    short8 af[MT][2], bf[NT][2];
#pragma unroll
    for (int mt = 0; mt < MT; ++mt)
#pragma unroll
      for (int kk = 0; kk < 2; ++kk) {
        int row = wr * (MT * 16) + mt * 16 + ql;
        int c = (kk * 4 + gq) ^ (row & 7);
        af[mt][kk] = *(const short8*)&As[row * 64 + c * 8];
      }
#pragma unroll
    for (int nt = 0; nt < NT; ++nt)
#pragma unroll
      for (int kk = 0; kk < 2; ++kk) {
        int row = wc * (NT * 16) + nt * 16 + ql;
        int c = (kk * 4 + gq) ^ (row & 7);
        bf[nt][kk] = *(const short8*)&Bs[row * 64 + c * 8];
      }
#pragma unroll
    for (int kk = 0; kk < 2; ++kk)
#pragma unroll
      for (int mt = 0; mt < MT; ++mt)
#pragma unroll
        for (int nt = 0; nt < NT; ++nt)
          acc[mt][nt] = MFMA16(af[mt][kk], bf[nt][kk], acc[mt][nt]);
    __syncthreads();
  }

#pragma unroll
  for (int mt = 0; mt < MT; ++mt)
#pragma unroll
    for (int nt = 0; nt < NT; ++nt)
#pragma unroll
      for (int r = 0; r < 4; ++r) {
        int m = m0 + wr * (MT * 16) + mt * 16 + gq * 4 + r;
        int n = n0 + wc * (NT * 16) + nt * 16 + ql;
        float v = acc[mt][nt][r];
        if (EPI == 0) {
          ((uint16_t*)Cv)[(size_t)m * N + n] = f2bf(v);
        } else {
          ((float*)Cv)[(size_t)m * N + n] = v + bias[n];
        }
      }
}

// merged projections: 3072 blocks.
//  b < 2048: qk = Xb @ Wqkt^T  [8192][4096]  (bx=b&31, by=b>>5)
//  else    : vt = Wvt @ Xb^T   [2048][8192]  (bx=rem&63, by=rem>>6)
__global__ __launch_bounds__(256) void proj_all_k(const uint16_t* __restrict__ Xb,
                                                  const uint16_t* __restrict__ Wqkt,
                                                  const uint16_t* __restrict__ Wvt,
                                                  uint16_t* __restrict__ qkw,
                                                  uint16_t* __restrict__ vtws) {
  __shared__ uint16_t As[128 * 64];
  __shared__ uint16_t Bs[4 * 32 * 64];
  const int b = blockIdx.x;
  if (b < 2048) {
    gemm_body<0, 4, 4>(Xb, Wqkt, qkw, nullptr, 8192, 4096, 256,
                       b & 31, b >> 5, As, Bs);
  } else {
    const int rem = b - 2048;
    gemm_body<0, 4, 4>(Wvt, Xb, vtws, nullptr, 2048, 8192, 256,
                       rem & 63, rem >> 6, As, Bs);
  }
}

// out projection: 64x64 tile (MT=2,NT=2), grid (4, 128) = 512 blocks (2/CU)
__global__ __launch_bounds__(256) void gemm_out_k(const uint16_t* __restrict__ A,
                                                  const uint16_t* __restrict__ Bt,
                                                  float* __restrict__ Cv,
                                                  const float* __restrict__ bias,
                                                  int M, int N, int K) {
  __shared__ uint16_t As[2 * 32 * 64];
  __shared__ uint16_t Bs[2 * 32 * 64];
  gemm_body<1, 2, 2>(A, Bt, Cv, bias, M, N, K, blockIdx.x, blockIdx.y, As, Bs);
}

// ---------------------------------------------------------------------------
// attn2: block = 256 thr (4 waves); wave owns 32 q-rows; block = 128 q-rows.
// 512 blocks -> 2 blocks/CU (independent barrier domains). KVBLK=32, 64 tiles.
// Swapped QK: S^T[key][q] = mfma(Kfrag, Qfrag); lane(q=l31) holds one q-col.
// Pipeline: body(t) = stage K(t+1),V(t) -> {QK(t) || PV(t-1)} -> SM(t) -> bar.
// K [32 keys][256 d] rows 512B, XOR32 (uniform bank quads). V [256 d][32 keys]
// rows 64B, swizzle g(d)=(d>>1)&3 -> uniform bank quads (4 lanes/quad).
__global__ __launch_bounds__(256, 2) void attn2_k(const uint16_t* __restrict__ qk,
                                                  const uint16_t* __restrict__ vtws,
                                                  uint16_t* __restrict__ ctx,
                                                  int b0, int nb) {
  __shared__ uint16_t Ks[2][32 * 256];   // 16KB/buf; chunk c at c^row
  __shared__ uint16_t Vts[2][256 * 32];  // 16KB/buf; chunk c at c^((d>>1)&3)
  const int S = 2048;
  // XCD-grouped decode: h == blockIdx%8 == XCD -> each XCD's L2 holds 1 head
  const int h = blockIdx.x & 7;
  const int t = blockIdx.x >> 3;
  const int bb = t >> 4, qb = t & 15;    // 16 q-blocks of 128 rows
  const int tid = threadIdx.x, w = tid >> 6, lane = tid & 63;
  const int l31 = lane & 31, hi = lane >> 5;
  const size_t SN = (size_t)nb * S;

  // ---- Q fragments (B-operand): Q[q=l31][ds*16 + hi*8 .. +7], 16 d-slots
  short8 qf[16];
  {
    const uint16_t* qrow =
        qk + (size_t)(bb * S + qb * 128 + w * 32 + l31) * 4096 + h * 256 + hi * 8;
#pragma unroll
    for (int ds = 0; ds < 16; ++ds) qf[ds] = *(const short8*)(qrow + ds * 16);
  }

  // ---- per-lane staging byte-offsets (hoisted; step per k-tile is uniform)
  uint32_t ok[4], ov[4];
#pragma unroll
  for (int j = 0; j < 4; ++j) {
    int s = (j * 4 + w) * 64 + lane;    // chunk 0..1023 within 16KB tile
    int krw = s >> 5, kc = s & 31;      // K: row(key 0..31), slot(0..31)
    int kgc = kc ^ krw;                 // inverse of XOR32 read swizzle
    ok[j] = (uint32_t)(((bb * S + krw) * 4096 + 2048 + h * 256 + kgc * 8) * 2);
    int d = s >> 2, vc = s & 3;         // V: row(d 0..255), slot(0..3)
    int cg = vc ^ ((d >> 1) & 3);       // uniform bank-quad swizzle
    ov[j] = (uint32_t)((((h * 256 + d) * SN) + (size_t)bb * S + cg * 8) * 2);
  }
  const uint32_t kstep = 32 * 4096 * 2;  // 32 key-rows (qk row stride 4096)
  const uint32_t vstep = 32 * 2;         // 32 key-cols

  const char* kgbase = (const char*)qk;
  const char* vgbase = (const char*)vtws;

  auto stageK = [&](int buf, int kb) {
#pragma unroll
    for (int j = 0; j < 4; ++j)
      gll16(kgbase + ok[j] + (uint32_t)kb * kstep, &Ks[buf][(j * 4 + w) * 512]);
  };
  auto stageV = [&](int buf, int kb) {
#pragma unroll
    for (int j = 0; j < 4; ++j)
      gll16(vgbase + ov[j] + (uint32_t)kb * vstep, &Vts[buf][(j * 4 + w) * 512]);
  };

  f32x16 cacc[8];
#pragma unroll
  for (int db = 0; db < 8; ++db)
#pragma unroll
    for (int r = 0; r < 16; ++r) cacc[db][r] = 0.f;
  float m_run = -3e38f, l_run = 0.f;
  short8 pa0, pa1;                       // packed P(t-1), persists across tiles

  const int kx = l31 << 4;               // K read XOR32 (row = l31)
  const int vx = ((l31 >> 1) & 3) << 4;  // V read swizzle g(d)=(d>>1)&3
  const int hi16 = hi << 4;

  f32x16 sA;

  // ---- QK(t) alone (prologue tile): 16-MFMA chain over K[cur]
  auto qk_only = [&](int cur) {
    const char* kr = (const char*)Ks[cur] + l31 * 512;
#pragma unroll
    for (int r = 0; r < 16; ++r) sA[r] = 0.f;
    __builtin_amdgcn_s_setprio(1);
#pragma unroll
    for (int i = 0; i < 16; ++i) {
      int off = (i * 32 + hi16) ^ kx;
      sA = MFMA32(*(const short8*)(kr + off), qf[i], sA);
    }
    __builtin_amdgcn_s_setprio(0);
  };

  // ---- QK(t) interleaved with PV(t-1) (pa0,pa1 against Vts[cur^1])
  auto qk_pv = [&](int cur) {
    const char* kr = (const char*)Ks[cur] + l31 * 512;
    const char* vb = (const char*)Vts[cur ^ 1];
#pragma unroll
    for (int r = 0; r < 16; ++r) sA[r] = 0.f;
    __builtin_amdgcn_s_setprio(1);
#pragma unroll
    for (int i = 0; i < 16; ++i) {
      int off = (i * 32 + hi16) ^ kx;
      sA = MFMA32(*(const short8*)(kr + off), qf[i], sA);
      const int ks = i >> 3, db = i & 7;       // compile-time in unroll
      int voff = ((ks * 2 + hi) << 4) ^ vx;
      short8 vf = *(const short8*)(vb + (db * 32 + l31) * 64 + voff);
      cacc[db] = MFMA32(ks ? pa1 : pa0, vf, cacc[db]);
    }
    __builtin_amdgcn_s_setprio(0);
  };

  // ---- PV(t) alone (epilogue tile), V in Vts[slot]
  auto pv_only = [&](int slot) {
    const char* vb = (const char*)Vts[slot];
    __builtin_amdgcn_s_setprio(1);
#pragma unroll
    for (int ks = 0; ks < 2; ++ks) {
      int voff = ((ks * 2 + hi) << 4) ^ vx;
      short8 p = ks ? pa1 : pa0;
#pragma unroll
      for (int db = 0; db < 8; ++db) {
        short8 vf = *(const short8*)(vb + (db * 32 + l31) * 64 + voff);
        cacc[db] = MFMA32(p, vf, cacc[db]);
      }
    }
    __builtin_amdgcn_s_setprio(0);
  };

  // ---- softmax (log2 domain) + pack into pa0,pa1
  auto sm_pack = [&]() {
    float pm = fmaxf(
        fmaxf(fmaxf(fmaxf(sA[0], sA[1]), fmaxf(sA[2], sA[3])),
              fmaxf(fmaxf(sA[4], sA[5]), fmaxf(sA[6], sA[7]))),
        fmaxf(fmaxf(fmaxf(sA[8], sA[9]), fmaxf(sA[10], sA[11])),
              fmaxf(fmaxf(sA[12], sA[13]), fmaxf(sA[14], sA[15]))));
    pm = fmaxf(pm, __shfl_xor(pm, 32));

    if (__any(pm - m_run > 8.0f)) {      // defer-max: rescale only on growth
      float mn = fmaxf(m_run, pm);
      float al = EXP2(m_run - mn);
      m_run = mn;
      l_run *= al;
#pragma unroll
      for (int r = 0; r < 16; ++r) {
        float a = __shfl(al, (r & 3) + 8 * (r >> 2) + 4 * hi);
#pragma unroll
        for (int db = 0; db < 8; ++db) cacc[db][r] *= a;
      }
    }

    float ps = 0.f;
#pragma unroll
    for (int r = 0; r < 16; ++r) { sA[r] = EXP2(sA[r] - m_run); ps += sA[r]; }
    ps += __shfl_xor(ps, 32);
    l_run += ps;

    uint32_t W[4][2];
#pragma unroll
    for (int g = 0; g < 4; ++g) {
      W[g][0] = cvtpk_bf16(sA[4 * g], sA[4 * g + 1]);
      W[g][1] = cvtpk_bf16(sA[4 * g + 2], sA[4 * g + 3]);
    }
    swap32(W[0][0], W[1][0]); swap32(W[0][1], W[1][1]);
    swap32(W[2][0], W[3][0]); swap32(W[2][1], W[3][1]);
    union U { uint32_t u[4]; short8 v; };
    U a0, a1;
    a0.u[0] = W[0][0]; a0.u[1] = W[0][1]; a0.u[2] = W[1][0]; a0.u[3] = W[1][1];
    a1.u[0] = W[2][0]; a1.u[1] = W[2][1]; a1.u[2] = W[3][0]; a1.u[3] = W[3][1];
    pa0 = a0.v; pa1 = a1.v;
  };

  // ---- pipeline
  stageK(0, 0);
  __syncthreads();                        // K(0) ready

  // body(0): stage K(1),V(0); QK(0); SM(0); barrier
  stageK(1, 1);
  stageV(0, 0);
  qk_only(0);
  sm_pack();
  __syncthreads();                        // K(1), V(0) ready

  for (int tt = 1; tt < 64; ++tt) {
    const int cur = tt & 1;
    if (tt < 63) stageK(cur ^ 1, tt + 1);
    stageV(cur, tt);
    qk_pv(cur);                           // QK(tt) || PV(tt-1)
    sm_pack();
    __syncthreads();
  }
  pv_only(1);                             // PV(63), V in Vts[63&1]

  // ---- epilogue: O[q][d] = cacc/l ; q in reg-dim -> broadcast 1/l per row
  float linv = 1.f / l_run;
  uint16_t* crow = ctx + (size_t)((b0 + bb) * S + qb * 128 + w * 32) * 2048 + h * 256;
#pragma unroll
  for (int r = 0; r < 16; ++r) {
    int qr = (r & 3) + 8 * (r >> 2) + 4 * hi;
    float lr = __shfl(linv, qr);
#pragma unroll
    for (int db = 0; db < 8; ++db)
      crow[(size_t)qr * 2048 + db * 32 + l31] = f2bf(cacc[db][r] * lr);
  }
}

// ---------------------------------------------------------------------------
extern "C" void kernel_launch(void* const* d_in, const int* in_sizes, int n_in,
                              void* d_out, int out_size, void* d_ws, size_t ws_size,
                              hipStream_t stream) {
  const float* X  = (const float*)d_in[0];
  const float* Wq = (const float*)d_in[1];
  const float* Wk = (const float*)d_in[2];
  const float* Wv = (const float*)d_in[3];
  const float* Wo = (const float*)d_in[4];
  const float* bo = (const float*)d_in[5];
  float* out = (float*)d_out;

  const int B = 4, S = 2048, Dm = 256, DH = 2048;
  (void)in_sizes; (void)n_in; (void)out_size; (void)ws_size;

  uint16_t* p = (uint16_t*)d_ws;
  uint16_t* Xb  = p; p += (size_t)B * S * Dm;
  uint16_t* Wqt = p; p += (size_t)DH * Dm;   // Wqt,Wkt,Wvt contiguous
  uint16_t* Wkt = p; p += (size_t)DH * Dm;
  uint16_t* Wvt = p; p += (size_t)DH * Dm;
  uint16_t* Wot = p; p += (size_t)Dm * DH;
  uint16_t* ctx = p; p += (size_t)B * S * DH;
  uint16_t* qkw = p; p += (size_t)B * S * (2 * DH);  // [8192][4096]
  uint16_t* vtws = p;                                // [2048][8192]
  (void)Wkt;

  // sqrt(log2e) folded into q,k scales -> scores in log2 domain
  const float qs = 0.25f * 1.2011224087864498f;

  // prep: X cast (2048 blocks) + all weight transpose-casts (512 blocks)
  prep_k<<<dim3(2560), 256, 0, stream>>>(X, Xb, Wq, Wk, Wv, Wo, Wqt, Wot, qs);
  // merged projections: qk [8192][4096] (2048 blocks) + vt [2048][8192] (1024)
  proj_all_k<<<dim3(3072), 256, 0, stream>>>(Xb, Wqt, Wvt, qkw, vtws);
  attn2_k<<<dim3(512), 256, 0, stream>>>(qkw, vtws, ctx, 0, B);
  // out projection: 64x64 tiles -> grid (4, 128) = 512 blocks (2 per CU)
  gemm_out_k<<<dim3(Dm / 64, (B * S) / 64), 256, 0, stream>>>(
      ctx, Wot, out, bo, B * S, Dm, DH);
}